// Round 18
// baseline (1377.658 us; speedup 1.0000x reference)
//
#include <hip/hip_runtime.h>
#include <hip/hip_bf16.h>

#define NPTS 8192
#define DIM 32
#define KKDE 32
#define KRIPS 16
#define DESTNUM 10

__device__ __forceinline__ unsigned long long shfl_xor_u64(unsigned long long v, int m) {
  int lo = __shfl_xor((int)(unsigned)(v & 0xFFFFFFFFull), m, 64);
  int hi = __shfl_xor((int)(unsigned)(v >> 32), m, 64);
  return (((unsigned long long)(unsigned)hi) << 32) | (unsigned)lo;
}

// ---------------- dtype detector: is x bf16-packed or f32? ----------------
__global__ __launch_bounds__(64) void detect_kernel(const unsigned short* __restrict__ x,
                                                    int* __restrict__ flag) {
  int lane = threadIdx.x;
  unsigned u = x[2 * lane];
  int e = (u >> 7) & 0xFF;
  bool pass = (e >= 110 && e <= 130);
  unsigned long long b = __ballot(pass);
  if (lane == 0) flag[0] = (__popcll(b) >= 32) ? 1 : 0;
}

// ---------------- transpose: xT[q][p] = x[p][q] as f32 (exact) ----------------
__global__ __launch_bounds__(256) void tr_kernel(const unsigned short* __restrict__ xh,
                                                 const int* __restrict__ flag,
                                                 float* __restrict__ xT) {
  int e = blockIdx.x * 256 + threadIdx.x;  // < NPTS*DIM
  if (e >= NPTS * DIM) return;
  int p = e >> 5, q = e & 31;
  float v;
  if (flag[0] != 0) v = __uint_as_float(((unsigned)xh[e]) << 16);
  else v = ((const float*)xh)[e];
  xT[q * NPTS + p] = v;
}

// ---------------- kNN v6: 8-wide float4-vectorized compute + bracket select ----------------
// One block per row i. Each thread computes 8 consecutive j per iteration with TWO
// dwordx4 loads per q. Per-j fma chains identical to R16/R17 (q ascending) -> d2
// bitwise identical; diagonal cancels exactly. Selection = R12-R17 proven verbatim.
__global__ __launch_bounds__(256) void knn_kernel(const float* __restrict__ xT,
                                                  float* __restrict__ kde,
                                                  int* __restrict__ rips) {
  __shared__ float row[NPTS];                  // 32 KB
  __shared__ int cnt[4];
  __shared__ unsigned long long cand[4 * 64];  // 2 KB
  __shared__ unsigned long long srt[4 * 32];   // 1 KB
  __shared__ unsigned long long fin[64];       // 512 B
  __shared__ float knnv[KKDE];
  __shared__ int knni[KKDE];
  __shared__ float xis[DIM];
  const int i = blockIdx.x;
  const int t = threadIdx.x;
  const int w = t >> 6, lane = t & 63;
  if (t < DIM) xis[t] = xT[t * NPTS + i];
  __syncthreads();
  float xi[DIM];
#pragma unroll
  for (int q = 0; q < DIM; ++q) xi[q] = xis[q];
  float sqi = 0.f;
#pragma unroll
  for (int q = 0; q < DIM; ++q) sqi = fmaf(xi[q], xi[q], sqi);
  const float4* xT4 = (const float4*)xT;
  float4* row4 = (float4*)row;
  for (int j8 = t; j8 < NPTS / 8; j8 += 256) {  // 4 iters/thread
    float d0 = 0.f, d1 = 0.f, d2 = 0.f, d3 = 0.f;
    float d4 = 0.f, d5 = 0.f, d6 = 0.f, d7 = 0.f;
    float s0 = 0.f, s1 = 0.f, s2 = 0.f, s3 = 0.f;
    float s4 = 0.f, s5 = 0.f, s6 = 0.f, s7 = 0.f;
#pragma unroll
    for (int q = 0; q < DIM; ++q) {
      float4 va = xT4[q * (NPTS / 4) + j8 * 2];
      float4 vb = xT4[q * (NPTS / 4) + j8 * 2 + 1];
      const float xq = xi[q];
      d0 = fmaf(xq, va.x, d0); s0 = fmaf(va.x, va.x, s0);
      d1 = fmaf(xq, va.y, d1); s1 = fmaf(va.y, va.y, s1);
      d2 = fmaf(xq, va.z, d2); s2 = fmaf(va.z, va.z, s2);
      d3 = fmaf(xq, va.w, d3); s3 = fmaf(va.w, va.w, s3);
      d4 = fmaf(xq, vb.x, d4); s4 = fmaf(vb.x, vb.x, s4);
      d5 = fmaf(xq, vb.y, d5); s5 = fmaf(vb.y, vb.y, s5);
      d6 = fmaf(xq, vb.z, d6); s6 = fmaf(vb.z, vb.z, s6);
      d7 = fmaf(xq, vb.w, d7); s7 = fmaf(vb.w, vb.w, s7);
    }
    // j==i component: v==xi[q] bitwise -> dot==sqi==sqj -> fmaf(-2,s,2s)==0 exactly
    float4 oa, ob;
    oa.x = fmaxf(fmaf(-2.f, d0, sqi + s0), 0.f);
    oa.y = fmaxf(fmaf(-2.f, d1, sqi + s1), 0.f);
    oa.z = fmaxf(fmaf(-2.f, d2, sqi + s2), 0.f);
    oa.w = fmaxf(fmaf(-2.f, d3, sqi + s3), 0.f);
    ob.x = fmaxf(fmaf(-2.f, d4, sqi + s4), 0.f);
    ob.y = fmaxf(fmaf(-2.f, d5, sqi + s5), 0.f);
    ob.z = fmaxf(fmaf(-2.f, d6, sqi + s6), 0.f);
    ob.w = fmaxf(fmaf(-2.f, d7, sqi + s7), 0.f);
    row4[j8 * 2] = oa;
    row4[j8 * 2 + 1] = ob;
  }
  __syncthreads();
  const float4* rowf4 = (const float4*)row;
  unsigned lo = 0u, hi = 0x7F800000u;
  int chi = 2048;
  while (chi > 64 && (hi - lo) > 1u) {
    const unsigned mid = lo + ((hi - lo) >> 1);
    int c = 0;
#pragma unroll
    for (int s = 0; s < 8; ++s) {
      float4 v = rowf4[(w << 9) + (s << 6) + lane];
      c += (__float_as_uint(v.x) <= mid) ? 1 : 0;
      c += (__float_as_uint(v.y) <= mid) ? 1 : 0;
      c += (__float_as_uint(v.z) <= mid) ? 1 : 0;
      c += (__float_as_uint(v.w) <= mid) ? 1 : 0;
    }
#pragma unroll
    for (int m = 1; m <= 32; m <<= 1) c += __shfl_xor(c, m, 64);
    if (c >= 32) { hi = mid; chi = c; } else { lo = mid; }
  }
  if (lane == 0) cnt[w] = 0;
  cand[(w << 6) | lane] = ~0ull;
#pragma unroll
  for (int s = 0; s < 8; ++s) {
    const int fidx = (w << 9) + (s << 6) + lane;
    float4 v = rowf4[fidx];
    const unsigned b0 = __float_as_uint(v.x), b1 = __float_as_uint(v.y);
    const unsigned b2 = __float_as_uint(v.z), b3 = __float_as_uint(v.w);
    if (b0 <= hi) {
      int pos = atomicAdd(&cnt[w], 1);
      if (pos < 64) cand[(w << 6) + pos] = (((unsigned long long)b0) << 32) | (unsigned)(fidx * 4 + 0);
    }
    if (b1 <= hi) {
      int pos = atomicAdd(&cnt[w], 1);
      if (pos < 64) cand[(w << 6) + pos] = (((unsigned long long)b1) << 32) | (unsigned)(fidx * 4 + 1);
    }
    if (b2 <= hi) {
      int pos = atomicAdd(&cnt[w], 1);
      if (pos < 64) cand[(w << 6) + pos] = (((unsigned long long)b2) << 32) | (unsigned)(fidx * 4 + 2);
    }
    if (b3 <= hi) {
      int pos = atomicAdd(&cnt[w], 1);
      if (pos < 64) cand[(w << 6) + pos] = (((unsigned long long)b3) << 32) | (unsigned)(fidx * 4 + 3);
    }
  }
  unsigned long long v = cand[(w << 6) | lane];
#pragma unroll
  for (int k = 2; k <= 64; k <<= 1) {
#pragma unroll
    for (int j = 32; j > 0; j >>= 1) {
      if (j >= k) continue;
      unsigned long long o = shfl_xor_u64(v, j);
      bool keepMin = (((lane & k) == 0) == ((lane & j) == 0));
      v = keepMin ? (v < o ? v : o) : (v > o ? v : o);
    }
  }
  if (lane < 32) srt[(w << 5) | lane] = v;
  __syncthreads();
  if (w < 2) {
    const unsigned long long* A = &srt[(w * 2) << 5];
    const unsigned long long* B = &srt[(w * 2 + 1) << 5];
    unsigned long long m = (lane < 32) ? A[lane] : B[63 - lane];
#pragma unroll
    for (int j = 32; j > 0; j >>= 1) {
      unsigned long long o = shfl_xor_u64(m, j);
      bool keepMin = ((lane & j) == 0);
      m = keepMin ? (m < o ? m : o) : (m > o ? m : o);
    }
    if (lane < 32) fin[(w << 5) | lane] = m;
  }
  __syncthreads();
  if (w == 0) {
    unsigned long long m = (lane < 32) ? fin[lane] : fin[32 + (63 - lane)];
#pragma unroll
    for (int j = 32; j > 0; j >>= 1) {
      unsigned long long o = shfl_xor_u64(m, j);
      bool keepMin = ((lane & j) == 0);
      m = keepMin ? (m < o ? m : o) : (m > o ? m : o);
    }
    if (lane < 32) {
      knnv[lane] = __uint_as_float((unsigned)(m >> 32));
      knni[lane] = (int)(m & 0x1FFFull);
    }
  }
  __syncthreads();
  if (t == 0) {
    float s = 0.f;
    for (int k = 0; k < KKDE; ++k) s += expf(knnv[k] * -0.015625f);  // exp(-d2/64), ascending
    kde[i] = s;
  }
  if (t < KRIPS) rips[i * KRIPS + t] = knni[t];
}

// ---------------- prep: fused max + normalize + death-init + argmin ----------------
// Single block. Reductions are order-independent -> kmax/argmin bitwise identical
// to the previous separate kernels (fmaxf strided+tree; u64-key min).
__global__ __launch_bounds__(256) void prep_kernel(float* __restrict__ kde,
                                                   int* __restrict__ death,
                                                   int* __restrict__ scali) {
  __shared__ float red[256];
  __shared__ unsigned long long red64[256];
  __shared__ float kmaxS;
  const int t = threadIdx.x;
  float m = 0.f;
  for (int p = t; p < NPTS; p += 256) m = fmaxf(m, kde[p]);
  red[t] = m;
  __syncthreads();
  for (int s = 128; s; s >>= 1) {
    if (t < s) red[t] = fmaxf(red[t], red[t + s]);
    __syncthreads();
  }
  if (t == 0) kmaxS = red[0];
  __syncthreads();
  const float km = kmaxS;
  unsigned long long best = ~0ull;
  for (int p = t; p < NPTS; p += 256) {
    float v = kde[p] / km;
    kde[p] = v;
    death[p] = -1;
    unsigned long long kk = (((unsigned long long)__float_as_uint(v)) << 32) | (unsigned)p;
    if (kk < best) best = kk;
  }
  red64[t] = best;
  __syncthreads();
  for (int s = 128; s; s >>= 1) {
    if (t < s && red64[t + s] < red64[t]) red64[t] = red64[t + s];
    __syncthreads();
  }
  if (t == 0) scali[0] = (int)(red64[0] & 0xFFFFFFFFull);
}

// ---------------- bitonic sort: order = argsort(-kde) (stable), rank = inverse ----------------
__global__ __launch_bounds__(256) void sort_kernel(const float* __restrict__ kde,
                                                   int* __restrict__ order,
                                                   int* __restrict__ rankp) {
  __shared__ float kv[NPTS];            // 32 KB
  __shared__ unsigned short ki[NPTS];   // 16 KB
  int t = threadIdx.x;
  for (int p = t; p < NPTS; p += 256) { kv[p] = kde[p]; ki[p] = (unsigned short)p; }
  __syncthreads();
  for (int size = 2; size <= NPTS; size <<= 1) {
    for (int stride = size >> 1; stride > 0; stride >>= 1) {
      for (int q = t; q < NPTS / 2; q += 256) {
        int lo = ((q & ~(stride - 1)) << 1) | (q & (stride - 1));
        int hi = lo + stride;
        float va = kv[lo], vb = kv[hi];
        int ia = ki[lo], ib = ki[hi];
        bool aFirst = (va > vb) || (va == vb && ia < ib);
        bool up = ((lo & size) == 0);
        if (up != aFirst) {
          kv[lo] = vb; kv[hi] = va;
          ki[lo] = (unsigned short)ib; ki[hi] = (unsigned short)ia;
        }
      }
      __syncthreads();
    }
  }
  for (int p = t; p < NPTS; p += 256) {
    int idx = ki[p];
    order[p] = idx;
    rankp[idx] = p;
  }
}

// ---------------- ordered neighbor stream (flat: [t*16 + kk]) ----------------
__global__ __launch_bounds__(256) void onbr_kernel(const int* __restrict__ order,
                                                   const int* __restrict__ rankp,
                                                   const int* __restrict__ rips,
                                                   unsigned short* __restrict__ onbr) {
  int e = blockIdx.x * 256 + threadIdx.x;  // e < NPTS*KRIPS
  if (e >= NPTS * KRIPS) return;
  int t = e >> 4, kk = e & 15;
  int i = order[t];
  int nbr = rips[i * KRIPS + kk];
  bool valid = rankp[nbr] < t;  // self has rank == t -> invalid, matching ref
  onbr[e] = (unsigned short)(nbr | (valid ? 0x8000 : 0));
}

// ---------------- persistence scan: eager union-find, slim fast path (R17) ----------------
// Change vs R17: relabel loop unrolled x4. Iterations are independent (every
// gather target is a fixed-point: dying d already points at true root g; entries
// rewritten early read as true roots) -> any interleaving correct; unroll
// overlaps the read->gather->write latency chains.
__global__ __launch_bounds__(64) void scan_kernel(const float* __restrict__ kde,
                                                  const int* __restrict__ order,
                                                  const unsigned short* __restrict__ onbr,
                                                  int* __restrict__ death,
                                                  const int* __restrict__ scali) {
  __shared__ float kdeS[NPTS];          // 32 KB
  __shared__ unsigned short root[NPTS]; // 16 KB
  const int lane = threadIdx.x;
  for (int p = lane; p < NPTS; p += 64) { kdeS[p] = kde[p]; root[p] = (unsigned short)p; }
  __syncthreads();
  const int sg = lane >> 4;
  const int4* ord4 = (const int4*)order;
  unsigned long long* root64 = (unsigned long long*)root;
  const int NG = NPTS / 4;

  auto process = [&](unsigned short cD, int4 cI) {
    const int di = cD;
    const int nbr = di & 0x1FFF;
    const bool valid = (di & 0x8000) != 0;
    const int iMine = (sg == 0) ? cI.x : (sg == 1) ? cI.y : (sg == 2) ? cI.z : cI.w;
    const int rd = root[nbr];           // single-hop find (invariant)
    int rv = valid ? rd : -1;
#pragma unroll
    for (int m = 1; m <= 8; m <<= 1) {
      int o = __shfl_xor(rv, m, 64);
      rv = (o > rv) ? o : rv;
    }
    const bool uniOk = !valid || (rd == rv);
    const bool collide =
        valid && (rd == cI.x || rd == cI.y || rd == cI.z || rd == cI.w);
    if (__all(uniOk && !collide)) {
      if ((lane & 15) == 0 && rv >= 0) root[iMine] = (unsigned short)rv;
    } else {
      const unsigned long long vbAll = __ballot(valid);
#pragma unroll
      for (int s = 0; s < 4; ++s) {
        const unsigned long long smask = 0xFFFFull << (16 * s);
        const int rc = (s == 0) ? rd : (int)root[nbr];
        unsigned long long vb = vbAll & smask;
        if (vb != 0) {
          int cl = __ffsll(vb) - 1;
          int gc = __builtin_amdgcn_readlane(rc, cl);
          unsigned long long uni = __ballot(!valid || rc == gc) & smask;
          if (uni == smask) {
            if (lane == 16 * s) root[iMine] = (unsigned short)gc;
          } else {
            float kr = valid ? kdeS[rc] : -1.0f;
            float mx = kr;
#pragma unroll
            for (int mk = 1; mk <= 8; mk <<= 1) mx = fmaxf(mx, __shfl_xor(mx, mk, 64));
            unsigned long long b = __ballot(valid && kr == mx) & smask;
            int kwin = __ffsll(b) - 1;
            int g = __builtin_amdgcn_readlane(rc, kwin);
            bool dying = (sg == s) && valid && (rc != g);
            if (dying) {
              root[rc] = (unsigned short)g;
              death[rc] = iMine;
            }
            if (lane == 16 * s) root[iMine] = (unsigned short)g;
            // restore depth<=1: halving pass; iterations independent -> unroll 4
#pragma unroll 4
            for (int it = 0; it < NPTS / 256; ++it) {
              int idx = it * 64 + lane;
              unsigned long long wv = root64[idx];
              unsigned e0 = (unsigned)(wv & 0xFFFFull);
              unsigned e1 = (unsigned)((wv >> 16) & 0xFFFFull);
              unsigned e2 = (unsigned)((wv >> 32) & 0xFFFFull);
              unsigned e3 = (unsigned)((wv >> 48) & 0xFFFFull);
              e0 = root[e0]; e1 = root[e1]; e2 = root[e2]; e3 = root[e3];
              root64[idx] = (unsigned long long)e0 | ((unsigned long long)e1 << 16) |
                            ((unsigned long long)e2 << 32) | ((unsigned long long)e3 << 48);
            }
          }
        }
      }
    }
  };

  unsigned short D0 = onbr[lane], D1 = onbr[64 + lane],
                 D2 = onbr[128 + lane], D3 = onbr[192 + lane];
  int4 I0 = ord4[0], I1 = ord4[1], I2 = ord4[2], I3 = ord4[3];
  for (int g = 0; g < NG; g += 4) {
    unsigned short N0 = 0, N1 = 0, N2 = 0, N3 = 0;
    int4 J0 = make_int4(0, 0, 0, 0), J1 = J0, J2 = J0, J3 = J0;
    if (g + 4 < NG) { N0 = onbr[(g + 4) * 64 + lane]; J0 = ord4[g + 4]; }
    if (g + 5 < NG) { N1 = onbr[(g + 5) * 64 + lane]; J1 = ord4[g + 5]; }
    if (g + 6 < NG) { N2 = onbr[(g + 6) * 64 + lane]; J2 = ord4[g + 6]; }
    if (g + 7 < NG) { N3 = onbr[(g + 7) * 64 + lane]; J3 = ord4[g + 7]; }
    process(D0, I0);
    process(D1, I1);
    process(D2, I2);
    process(D3, I3);
    D0 = N0; D1 = N1; D2 = N2; D3 = N3;
    I0 = J0; I1 = J1; I2 = J2; I3 = J3;
  }
  if (lane == 0) death[order[0]] = scali[0];  // essential pair
}

// ---------------- loss: top-10 persistence via LDS-staged pers (R17 proven) ----------------
__global__ __launch_bounds__(256) void loss_kernel(const float* __restrict__ kde,
                                                   const int* __restrict__ death,
                                                   float* __restrict__ out) {
  __shared__ float persS[NPTS];  // 32 KB
  __shared__ float redv[256];
  __shared__ int redi[256];
  const int t = threadIdx.x;
  for (int p = t; p < NPTS; p += 256) {
    int d = death[p];
    persS[p] = (d < 0) ? -__builtin_inff() : kde[p] - kde[d];
  }
  __syncthreads();
  int chosen[DESTNUM];
  for (int k = 0; k < DESTNUM; ++k) {
    float bv = -__builtin_inff();
    int bi = 1 << 30;
    for (int p = t; p < NPTS; p += 256) {
      float pv = persS[p];
      if (pv > bv || (pv == bv && p < bi)) { bv = pv; bi = p; }
    }
    redv[t] = bv; redi[t] = bi;
    __syncthreads();
    for (int s = 128; s; s >>= 1) {
      if (t < s) {
        if (redv[t + s] > redv[t] || (redv[t + s] == redv[t] && redi[t + s] < redi[t])) {
          redv[t] = redv[t + s];
          redi[t] = redi[t + s];
        }
      }
      __syncthreads();
    }
    chosen[k] = redi[0];
    if (t == 0 && redi[0] < NPTS) persS[redi[0]] = -__builtin_inff();
    __syncthreads();
  }
  float acc = 0.f;
  for (int p = t; p < NPTS; p += 256) {
    int d = death[p];
    if (d < 0) continue;
    bool sal = false;
    for (int c = 0; c < DESTNUM; ++c) sal |= (chosen[c] == p);
    float dv = kde[d];
    float kp = kde[p];
    acc += sal ? ((kp - 1.f) * (kp - 1.f) + dv * dv) : (kp - dv) * (kp - dv);
  }
  redv[t] = acc;
  __syncthreads();
  for (int s = 128; s; s >>= 1) {
    if (t < s) redv[t] += redv[t + s];
    __syncthreads();
  }
  if (t == 0) out[0] = redv[0];
}

extern "C" void kernel_launch(void* const* d_in, const int* in_sizes, int n_in,
                              void* d_out, int out_size, void* d_ws, size_t ws_size,
                              hipStream_t stream) {
  const unsigned short* x = (const unsigned short*)d_in[0];

  float* xT = (float*)d_ws;                       // NPTS*DIM f32 transposed (1 MB)
  float* kde = xT + NPTS * DIM;                   // NPTS f32
  int* scali = (int*)(kde + NPTS);                // [0] = argmin idx
  int* flag = scali + 64;                         // [0] = dtype flag (1=bf16, 0=f32)
  int* order = flag + 64;                         // NPTS (16B-aligned for int4 loads)
  int* rankp = order + NPTS;                      // NPTS
  int* rips = rankp + NPTS;                       // NPTS*KRIPS
  unsigned short* onbr = (unsigned short*)(rips + NPTS * KRIPS);  // NPTS*KRIPS u16
  int* death = (int*)(onbr + NPTS * KRIPS);       // NPTS

  hipLaunchKernelGGL(detect_kernel, dim3(1), dim3(64), 0, stream, x, flag);
  hipLaunchKernelGGL(tr_kernel, dim3(NPTS * DIM / 256), dim3(256), 0, stream, x, flag, xT);
  hipLaunchKernelGGL(knn_kernel, dim3(NPTS), dim3(256), 0, stream, xT, kde, rips);
  hipLaunchKernelGGL(prep_kernel, dim3(1), dim3(256), 0, stream, kde, death, scali);
  hipLaunchKernelGGL(sort_kernel, dim3(1), dim3(256), 0, stream, kde, order, rankp);
  hipLaunchKernelGGL(onbr_kernel, dim3(NPTS * KRIPS / 256), dim3(256), 0, stream,
                     order, rankp, rips, onbr);
  hipLaunchKernelGGL(scan_kernel, dim3(1), dim3(64), 0, stream, kde, order, onbr, death, scali);
  hipLaunchKernelGGL(loss_kernel, dim3(1), dim3(256), 0, stream, kde, death, (float*)d_out);
}

// Round 19
// 1335.238 us; speedup vs baseline: 1.0318x; 1.0318x over previous
//
#include <hip/hip_runtime.h>
#include <hip/hip_bf16.h>

#define NPTS 8192
#define DIM 32
#define KKDE 32
#define KRIPS 16
#define DESTNUM 10

__device__ __forceinline__ unsigned long long shfl_xor_u64(unsigned long long v, int m) {
  int lo = __shfl_xor((int)(unsigned)(v & 0xFFFFFFFFull), m, 64);
  int hi = __shfl_xor((int)(unsigned)(v >> 32), m, 64);
  return (((unsigned long long)(unsigned)hi) << 32) | (unsigned)lo;
}

// ---------------- dtype detector: is x bf16-packed or f32? ----------------
__global__ __launch_bounds__(64) void detect_kernel(const unsigned short* __restrict__ x,
                                                    int* __restrict__ flag) {
  int lane = threadIdx.x;
  unsigned u = x[2 * lane];
  int e = (u >> 7) & 0xFF;
  bool pass = (e >= 110 && e <= 130);
  unsigned long long b = __ballot(pass);
  if (lane == 0) flag[0] = (__popcll(b) >= 32) ? 1 : 0;
}

// ---------------- transpose: xT[q][p] = x[p][q] as f32 (exact) ----------------
__global__ __launch_bounds__(256) void tr_kernel(const unsigned short* __restrict__ xh,
                                                 const int* __restrict__ flag,
                                                 float* __restrict__ xT) {
  int e = blockIdx.x * 256 + threadIdx.x;  // < NPTS*DIM
  if (e >= NPTS * DIM) return;
  int p = e >> 5, q = e & 31;
  float v;
  if (flag[0] != 0) v = __uint_as_float(((unsigned)xh[e]) << 16);
  else v = ((const float*)xh)[e];
  xT[q * NPTS + p] = v;
}

// ---------------- kNN v5 (R16/R17 proven fastest): 4-wide vectorized + bracket select ----------------
__global__ __launch_bounds__(256) void knn_kernel(const float* __restrict__ xT,
                                                  float* __restrict__ kde,
                                                  int* __restrict__ rips) {
  __shared__ float row[NPTS];                  // 32 KB
  __shared__ int cnt[4];
  __shared__ unsigned long long cand[4 * 64];  // 2 KB
  __shared__ unsigned long long srt[4 * 32];   // 1 KB
  __shared__ unsigned long long fin[64];       // 512 B
  __shared__ float knnv[KKDE];
  __shared__ int knni[KKDE];
  __shared__ float xis[DIM];
  const int i = blockIdx.x;
  const int t = threadIdx.x;
  const int w = t >> 6, lane = t & 63;
  if (t < DIM) xis[t] = xT[t * NPTS + i];
  __syncthreads();
  float xi[DIM];
#pragma unroll
  for (int q = 0; q < DIM; ++q) xi[q] = xis[q];
  float sqi = 0.f;
#pragma unroll
  for (int q = 0; q < DIM; ++q) sqi = fmaf(xi[q], xi[q], sqi);
  const float4* xT4 = (const float4*)xT;
  float4* row4 = (float4*)row;
  for (int j4 = t; j4 < NPTS / 4; j4 += 256) {
    float d0 = 0.f, d1 = 0.f, d2 = 0.f, d3 = 0.f;
    float s0 = 0.f, s1 = 0.f, s2 = 0.f, s3 = 0.f;
#pragma unroll
    for (int q = 0; q < DIM; ++q) {
      float4 v = xT4[q * (NPTS / 4) + j4];
      const float xq = xi[q];
      d0 = fmaf(xq, v.x, d0); s0 = fmaf(v.x, v.x, s0);
      d1 = fmaf(xq, v.y, d1); s1 = fmaf(v.y, v.y, s1);
      d2 = fmaf(xq, v.z, d2); s2 = fmaf(v.z, v.z, s2);
      d3 = fmaf(xq, v.w, d3); s3 = fmaf(v.w, v.w, s3);
    }
    // j==i component: v==xi[q] bitwise -> dot==sqi==sqj -> fmaf(-2,s,2s)==0 exactly
    float4 o;
    o.x = fmaxf(fmaf(-2.f, d0, sqi + s0), 0.f);
    o.y = fmaxf(fmaf(-2.f, d1, sqi + s1), 0.f);
    o.z = fmaxf(fmaf(-2.f, d2, sqi + s2), 0.f);
    o.w = fmaxf(fmaf(-2.f, d3, sqi + s3), 0.f);
    row4[j4] = o;
  }
  __syncthreads();
  const float4* rowf4 = (const float4*)row;
  unsigned lo = 0u, hi = 0x7F800000u;
  int chi = 2048;
  while (chi > 64 && (hi - lo) > 1u) {
    const unsigned mid = lo + ((hi - lo) >> 1);
    int c = 0;
#pragma unroll
    for (int s = 0; s < 8; ++s) {
      float4 v = rowf4[(w << 9) + (s << 6) + lane];
      c += (__float_as_uint(v.x) <= mid) ? 1 : 0;
      c += (__float_as_uint(v.y) <= mid) ? 1 : 0;
      c += (__float_as_uint(v.z) <= mid) ? 1 : 0;
      c += (__float_as_uint(v.w) <= mid) ? 1 : 0;
    }
#pragma unroll
    for (int m = 1; m <= 32; m <<= 1) c += __shfl_xor(c, m, 64);
    if (c >= 32) { hi = mid; chi = c; } else { lo = mid; }
  }
  if (lane == 0) cnt[w] = 0;
  cand[(w << 6) | lane] = ~0ull;
#pragma unroll
  for (int s = 0; s < 8; ++s) {
    const int fidx = (w << 9) + (s << 6) + lane;
    float4 v = rowf4[fidx];
    const unsigned b0 = __float_as_uint(v.x), b1 = __float_as_uint(v.y);
    const unsigned b2 = __float_as_uint(v.z), b3 = __float_as_uint(v.w);
    if (b0 <= hi) {
      int pos = atomicAdd(&cnt[w], 1);
      if (pos < 64) cand[(w << 6) + pos] = (((unsigned long long)b0) << 32) | (unsigned)(fidx * 4 + 0);
    }
    if (b1 <= hi) {
      int pos = atomicAdd(&cnt[w], 1);
      if (pos < 64) cand[(w << 6) + pos] = (((unsigned long long)b1) << 32) | (unsigned)(fidx * 4 + 1);
    }
    if (b2 <= hi) {
      int pos = atomicAdd(&cnt[w], 1);
      if (pos < 64) cand[(w << 6) + pos] = (((unsigned long long)b2) << 32) | (unsigned)(fidx * 4 + 2);
    }
    if (b3 <= hi) {
      int pos = atomicAdd(&cnt[w], 1);
      if (pos < 64) cand[(w << 6) + pos] = (((unsigned long long)b3) << 32) | (unsigned)(fidx * 4 + 3);
    }
  }
  unsigned long long v = cand[(w << 6) | lane];
#pragma unroll
  for (int k = 2; k <= 64; k <<= 1) {
#pragma unroll
    for (int j = 32; j > 0; j >>= 1) {
      if (j >= k) continue;
      unsigned long long o = shfl_xor_u64(v, j);
      bool keepMin = (((lane & k) == 0) == ((lane & j) == 0));
      v = keepMin ? (v < o ? v : o) : (v > o ? v : o);
    }
  }
  if (lane < 32) srt[(w << 5) | lane] = v;
  __syncthreads();
  if (w < 2) {
    const unsigned long long* A = &srt[(w * 2) << 5];
    const unsigned long long* B = &srt[(w * 2 + 1) << 5];
    unsigned long long m = (lane < 32) ? A[lane] : B[63 - lane];
#pragma unroll
    for (int j = 32; j > 0; j >>= 1) {
      unsigned long long o = shfl_xor_u64(m, j);
      bool keepMin = ((lane & j) == 0);
      m = keepMin ? (m < o ? m : o) : (m > o ? m : o);
    }
    if (lane < 32) fin[(w << 5) | lane] = m;
  }
  __syncthreads();
  if (w == 0) {
    unsigned long long m = (lane < 32) ? fin[lane] : fin[32 + (63 - lane)];
#pragma unroll
    for (int j = 32; j > 0; j >>= 1) {
      unsigned long long o = shfl_xor_u64(m, j);
      bool keepMin = ((lane & j) == 0);
      m = keepMin ? (m < o ? m : o) : (m > o ? m : o);
    }
    if (lane < 32) {
      knnv[lane] = __uint_as_float((unsigned)(m >> 32));
      knni[lane] = (int)(m & 0x1FFFull);
    }
  }
  __syncthreads();
  if (t == 0) {
    float s = 0.f;
    for (int k = 0; k < KKDE; ++k) s += expf(knnv[k] * -0.015625f);  // exp(-d2/64), ascending
    kde[i] = s;
  }
  if (t < KRIPS) rips[i * KRIPS + t] = knni[t];
}

// ---------------- prep: fused max + normalize + death-init + argmin (R18 proven) ----------------
__global__ __launch_bounds__(256) void prep_kernel(float* __restrict__ kde,
                                                   int* __restrict__ death,
                                                   int* __restrict__ scali) {
  __shared__ float red[256];
  __shared__ unsigned long long red64[256];
  __shared__ float kmaxS;
  const int t = threadIdx.x;
  float m = 0.f;
  for (int p = t; p < NPTS; p += 256) m = fmaxf(m, kde[p]);
  red[t] = m;
  __syncthreads();
  for (int s = 128; s; s >>= 1) {
    if (t < s) red[t] = fmaxf(red[t], red[t + s]);
    __syncthreads();
  }
  if (t == 0) kmaxS = red[0];
  __syncthreads();
  const float km = kmaxS;
  unsigned long long best = ~0ull;
  for (int p = t; p < NPTS; p += 256) {
    float v = kde[p] / km;
    kde[p] = v;
    death[p] = -1;
    unsigned long long kk = (((unsigned long long)__float_as_uint(v)) << 32) | (unsigned)p;
    if (kk < best) best = kk;
  }
  red64[t] = best;
  __syncthreads();
  for (int s = 128; s; s >>= 1) {
    if (t < s && red64[t + s] < red64[t]) red64[t] = red64[t + s];
    __syncthreads();
  }
  if (t == 0) scali[0] = (int)(red64[0] & 0xFFFFFFFFull);
}

// ---------------- bitonic sort: order = argsort(-kde) (stable), rank = inverse ----------------
__global__ __launch_bounds__(256) void sort_kernel(const float* __restrict__ kde,
                                                   int* __restrict__ order,
                                                   int* __restrict__ rankp) {
  __shared__ float kv[NPTS];            // 32 KB
  __shared__ unsigned short ki[NPTS];   // 16 KB
  int t = threadIdx.x;
  for (int p = t; p < NPTS; p += 256) { kv[p] = kde[p]; ki[p] = (unsigned short)p; }
  __syncthreads();
  for (int size = 2; size <= NPTS; size <<= 1) {
    for (int stride = size >> 1; stride > 0; stride >>= 1) {
      for (int q = t; q < NPTS / 2; q += 256) {
        int lo = ((q & ~(stride - 1)) << 1) | (q & (stride - 1));
        int hi = lo + stride;
        float va = kv[lo], vb = kv[hi];
        int ia = ki[lo], ib = ki[hi];
        bool aFirst = (va > vb) || (va == vb && ia < ib);
        bool up = ((lo & size) == 0);
        if (up != aFirst) {
          kv[lo] = vb; kv[hi] = va;
          ki[lo] = (unsigned short)ib; ki[hi] = (unsigned short)ia;
        }
      }
      __syncthreads();
    }
  }
  for (int p = t; p < NPTS; p += 256) {
    int idx = ki[p];
    order[p] = idx;
    rankp[idx] = p;
  }
}

// ---------------- ordered neighbor stream (flat: [t*16 + kk]) ----------------
__global__ __launch_bounds__(256) void onbr_kernel(const int* __restrict__ order,
                                                   const int* __restrict__ rankp,
                                                   const int* __restrict__ rips,
                                                   unsigned short* __restrict__ onbr) {
  int e = blockIdx.x * 256 + threadIdx.x;  // e < NPTS*KRIPS
  if (e >= NPTS * KRIPS) return;
  int t = e >> 4, kk = e & 15;
  int i = order[t];
  int nbr = rips[i * KRIPS + kk];
  bool valid = rankp[nbr] < t;  // self has rank == t -> invalid, matching ref
  onbr[e] = (unsigned short)(nbr | (valid ? 0x8000 : 0));
}

// ---------------- persistence scan: eager union-find, slim fast path (R18 proven, 728us) ----------------
__global__ __launch_bounds__(64) void scan_kernel(const float* __restrict__ kde,
                                                  const int* __restrict__ order,
                                                  const unsigned short* __restrict__ onbr,
                                                  int* __restrict__ death,
                                                  const int* __restrict__ scali) {
  __shared__ float kdeS[NPTS];          // 32 KB
  __shared__ unsigned short root[NPTS]; // 16 KB
  const int lane = threadIdx.x;
  for (int p = lane; p < NPTS; p += 64) { kdeS[p] = kde[p]; root[p] = (unsigned short)p; }
  __syncthreads();
  const int sg = lane >> 4;
  const int4* ord4 = (const int4*)order;
  unsigned long long* root64 = (unsigned long long*)root;
  const int NG = NPTS / 4;

  auto process = [&](unsigned short cD, int4 cI) {
    const int di = cD;
    const int nbr = di & 0x1FFF;
    const bool valid = (di & 0x8000) != 0;
    const int iMine = (sg == 0) ? cI.x : (sg == 1) ? cI.y : (sg == 2) ? cI.z : cI.w;
    const int rd = root[nbr];           // single-hop find (invariant)
    int rv = valid ? rd : -1;
#pragma unroll
    for (int m = 1; m <= 8; m <<= 1) {
      int o = __shfl_xor(rv, m, 64);
      rv = (o > rv) ? o : rv;
    }
    const bool uniOk = !valid || (rd == rv);
    const bool collide =
        valid && (rd == cI.x || rd == cI.y || rd == cI.z || rd == cI.w);
    if (__all(uniOk && !collide)) {
      if ((lane & 15) == 0 && rv >= 0) root[iMine] = (unsigned short)rv;
    } else {
      const unsigned long long vbAll = __ballot(valid);
#pragma unroll
      for (int s = 0; s < 4; ++s) {
        const unsigned long long smask = 0xFFFFull << (16 * s);
        const int rc = (s == 0) ? rd : (int)root[nbr];
        unsigned long long vb = vbAll & smask;
        if (vb != 0) {
          int cl = __ffsll(vb) - 1;
          int gc = __builtin_amdgcn_readlane(rc, cl);
          unsigned long long uni = __ballot(!valid || rc == gc) & smask;
          if (uni == smask) {
            if (lane == 16 * s) root[iMine] = (unsigned short)gc;
          } else {
            float kr = valid ? kdeS[rc] : -1.0f;
            float mx = kr;
#pragma unroll
            for (int mk = 1; mk <= 8; mk <<= 1) mx = fmaxf(mx, __shfl_xor(mx, mk, 64));
            unsigned long long b = __ballot(valid && kr == mx) & smask;
            int kwin = __ffsll(b) - 1;
            int g = __builtin_amdgcn_readlane(rc, kwin);
            bool dying = (sg == s) && valid && (rc != g);
            if (dying) {
              root[rc] = (unsigned short)g;
              death[rc] = iMine;
            }
            if (lane == 16 * s) root[iMine] = (unsigned short)g;
            // restore depth<=1: halving pass; iterations independent -> unroll 4
#pragma unroll 4
            for (int it = 0; it < NPTS / 256; ++it) {
              int idx = it * 64 + lane;
              unsigned long long wv = root64[idx];
              unsigned e0 = (unsigned)(wv & 0xFFFFull);
              unsigned e1 = (unsigned)((wv >> 16) & 0xFFFFull);
              unsigned e2 = (unsigned)((wv >> 32) & 0xFFFFull);
              unsigned e3 = (unsigned)((wv >> 48) & 0xFFFFull);
              e0 = root[e0]; e1 = root[e1]; e2 = root[e2]; e3 = root[e3];
              root64[idx] = (unsigned long long)e0 | ((unsigned long long)e1 << 16) |
                            ((unsigned long long)e2 << 32) | ((unsigned long long)e3 << 48);
            }
          }
        }
      }
    }
  };

  unsigned short D0 = onbr[lane], D1 = onbr[64 + lane],
                 D2 = onbr[128 + lane], D3 = onbr[192 + lane];
  int4 I0 = ord4[0], I1 = ord4[1], I2 = ord4[2], I3 = ord4[3];
  for (int g = 0; g < NG; g += 4) {
    unsigned short N0 = 0, N1 = 0, N2 = 0, N3 = 0;
    int4 J0 = make_int4(0, 0, 0, 0), J1 = J0, J2 = J0, J3 = J0;
    if (g + 4 < NG) { N0 = onbr[(g + 4) * 64 + lane]; J0 = ord4[g + 4]; }
    if (g + 5 < NG) { N1 = onbr[(g + 5) * 64 + lane]; J1 = ord4[g + 5]; }
    if (g + 6 < NG) { N2 = onbr[(g + 6) * 64 + lane]; J2 = ord4[g + 6]; }
    if (g + 7 < NG) { N3 = onbr[(g + 7) * 64 + lane]; J3 = ord4[g + 7]; }
    process(D0, I0);
    process(D1, I1);
    process(D2, I2);
    process(D3, I3);
    D0 = N0; D1 = N1; D2 = N2; D3 = N3;
    I0 = J0; I1 = J1; I2 = J2; I3 = J3;
  }
  if (lane == 0) death[order[0]] = scali[0];  // essential pair
}

// ---------------- loss: top-10 persistence via LDS-staged pers (R17 proven) ----------------
__global__ __launch_bounds__(256) void loss_kernel(const float* __restrict__ kde,
                                                   const int* __restrict__ death,
                                                   float* __restrict__ out) {
  __shared__ float persS[NPTS];  // 32 KB
  __shared__ float redv[256];
  __shared__ int redi[256];
  const int t = threadIdx.x;
  for (int p = t; p < NPTS; p += 256) {
    int d = death[p];
    persS[p] = (d < 0) ? -__builtin_inff() : kde[p] - kde[d];
  }
  __syncthreads();
  int chosen[DESTNUM];
  for (int k = 0; k < DESTNUM; ++k) {
    float bv = -__builtin_inff();
    int bi = 1 << 30;
    for (int p = t; p < NPTS; p += 256) {
      float pv = persS[p];
      if (pv > bv || (pv == bv && p < bi)) { bv = pv; bi = p; }
    }
    redv[t] = bv; redi[t] = bi;
    __syncthreads();
    for (int s = 128; s; s >>= 1) {
      if (t < s) {
        if (redv[t + s] > redv[t] || (redv[t + s] == redv[t] && redi[t + s] < redi[t])) {
          redv[t] = redv[t + s];
          redi[t] = redi[t + s];
        }
      }
      __syncthreads();
    }
    chosen[k] = redi[0];
    if (t == 0 && redi[0] < NPTS) persS[redi[0]] = -__builtin_inff();
    __syncthreads();
  }
  float acc = 0.f;
  for (int p = t; p < NPTS; p += 256) {
    int d = death[p];
    if (d < 0) continue;
    bool sal = false;
    for (int c = 0; c < DESTNUM; ++c) sal |= (chosen[c] == p);
    float dv = kde[d];
    float kp = kde[p];
    acc += sal ? ((kp - 1.f) * (kp - 1.f) + dv * dv) : (kp - dv) * (kp - dv);
  }
  redv[t] = acc;
  __syncthreads();
  for (int s = 128; s; s >>= 1) {
    if (t < s) redv[t] += redv[t + s];
    __syncthreads();
  }
  if (t == 0) out[0] = redv[0];
}

extern "C" void kernel_launch(void* const* d_in, const int* in_sizes, int n_in,
                              void* d_out, int out_size, void* d_ws, size_t ws_size,
                              hipStream_t stream) {
  const unsigned short* x = (const unsigned short*)d_in[0];

  float* xT = (float*)d_ws;                       // NPTS*DIM f32 transposed (1 MB)
  float* kde = xT + NPTS * DIM;                   // NPTS f32
  int* scali = (int*)(kde + NPTS);                // [0] = argmin idx
  int* flag = scali + 64;                         // [0] = dtype flag (1=bf16, 0=f32)
  int* order = flag + 64;                         // NPTS (16B-aligned for int4 loads)
  int* rankp = order + NPTS;                      // NPTS
  int* rips = rankp + NPTS;                       // NPTS*KRIPS
  unsigned short* onbr = (unsigned short*)(rips + NPTS * KRIPS);  // NPTS*KRIPS u16
  int* death = (int*)(onbr + NPTS * KRIPS);       // NPTS

  hipLaunchKernelGGL(detect_kernel, dim3(1), dim3(64), 0, stream, x, flag);
  hipLaunchKernelGGL(tr_kernel, dim3(NPTS * DIM / 256), dim3(256), 0, stream, x, flag, xT);
  hipLaunchKernelGGL(knn_kernel, dim3(NPTS), dim3(256), 0, stream, xT, kde, rips);
  hipLaunchKernelGGL(prep_kernel, dim3(1), dim3(256), 0, stream, kde, death, scali);
  hipLaunchKernelGGL(sort_kernel, dim3(1), dim3(256), 0, stream, kde, order, rankp);
  hipLaunchKernelGGL(onbr_kernel, dim3(NPTS * KRIPS / 256), dim3(256), 0, stream,
                     order, rankp, rips, onbr);
  hipLaunchKernelGGL(scan_kernel, dim3(1), dim3(64), 0, stream, kde, order, onbr, death, scali);
  hipLaunchKernelGGL(loss_kernel, dim3(1), dim3(256), 0, stream, kde, death, (float*)d_out);
}